// Round 9
// baseline (183.740 us; speedup 1.0000x reference)
//
#include <hip/hip_runtime.h>
#include <math.h>

// SpaTrans on MI355X. R9: 4-launch pipeline.
//  k_prep     = weight cast/permute + input transpose
//  k_tok_qkv  = token-embed + LN1 + QKV (unchanged from R8)
//  k_attn     = pure attention, ZERO LDS, output pre-packed as out_proj
//               B-operand (AOp); mask hoisted to bitmask; 1/sum deferred
//  k_oln_ffn  = out_proj + LN2 + ff1 + relu + ff2 + residual + conv
// Splits R8's 12-phase latency-bound k_attn_ffn (56.6us, MfmaUtil 5%).
#define Lh 32
#define Lw 32
#define LL 1024
#define BN 25
#define EE 128
#define CC 64
#define NHD 8
#define DH 16
#define FFD 256
#define MROWS 25600

typedef __attribute__((ext_vector_type(8))) short short8;
typedef __attribute__((ext_vector_type(4))) float f32x4;

__device__ inline ushort f2b(float x) {
    union { float f; unsigned u; } v; v.f = x;
    unsigned r = (v.u + 0x7fffu + ((v.u >> 16) & 1u)) >> 16;
    return (ushort)r;
}
__device__ inline float b2f(ushort u) {
    union { unsigned u; float f; } v; v.u = ((unsigned)u) << 16;
    return v.f;
}

// ---------------------------------------------------------------------------
// Weight layout (ushorts). W2 K-reordered (k'=tap*64+ch). WO/W2F/WC k-PERMUTED
// (kpos=c*32+q*8+i <-> orig k=(2c+(i>>2))*16+q*4+(i&3)). Q rows pre-scaled 0.25.
// ---------------------------------------------------------------------------
#define OFF_W2  0
#define OFF_WQK 73728
#define OFF_WV  106496
#define OFF_WO  122880
#define OFF_W1  139264
#define OFF_W2F 172032
#define OFF_WC  204800
#define W_TOTAL 212992
#define PREPW_BLOCKS 832

__global__ __launch_bounds__(256) void k_prep(
    const float* __restrict__ w_mlp, const float* __restrict__ in_proj,
    const float* __restrict__ out_proj, const float* __restrict__ ff_w1,
    const float* __restrict__ ff_w2, const float* __restrict__ conv_w,
    const float* __restrict__ buf, const float* __restrict__ spa,
    ushort* __restrict__ Wb, ushort* __restrict__ T, ushort* __restrict__ S)
{
    __shared__ float t0[64][33];
    __shared__ float t1[64][33];
    const int t = threadIdx.x;
    if (blockIdx.x < PREPW_BLOCKS) {
        int i = blockIdx.x * 256 + t;
        if (i >= W_TOTAL) return;
        if (i < 73728) {
            int e = i / 576, k = i - e * 576;
            int tap = k >> 6, ch = k & 63;
            Wb[OFF_W2 + i] = f2b(w_mlp[e * 576 + ch * 9 + tap]);
            return;
        }
        i -= 73728;
        if (i < 32768) {   // WQK; Q rows pre-scaled by 1/sqrt(16)
            float v = in_proj[i];
            Wb[OFF_WQK + i] = f2b(i < 16384 ? v * 0.25f : v);
            return;
        }
        i -= 32768;
        if (i < 16384) { Wb[OFF_WV + i] = f2b(in_proj[32768 + i]); return; }
        i -= 16384;
        if (i < 16384) {   // WO, k-permuted (K=128)
            int e = i >> 7, kpos = i & 127;
            int c = kpos >> 5, q = (kpos >> 3) & 3, ii = kpos & 7;
            int orig = (2 * c + (ii >> 2)) * 16 + q * 4 + (ii & 3);
            Wb[OFF_WO + i] = f2b(out_proj[e * 128 + orig]);
            return;
        }
        i -= 16384;
        if (i < 32768) { Wb[OFF_W1 + i] = f2b(ff_w1[i]); return; }
        i -= 32768;
        if (i < 32768) {   // W2F, k-permuted (K=256)
            int e = i >> 8, kpos = i & 255;
            int c = kpos >> 5, q = (kpos >> 3) & 3, ii = kpos & 7;
            int orig = (2 * c + (ii >> 2)) * 16 + q * 4 + (ii & 3);
            Wb[OFF_W2F + i] = f2b(ff_w2[e * 256 + orig]);
            return;
        }
        i -= 32768;
        {                  // WC, k-permuted (K=128)
            int o = i >> 7, kpos = i & 127;
            int c = kpos >> 5, q = (kpos >> 3) & 3, ii = kpos & 7;
            int orig = (2 * c + (ii >> 2)) * 16 + q * 4 + (ii & 3);
            Wb[OFF_WC + i] = f2b(conv_w[o * 128 + orig]);
        }
        return;
    }
    // ---- input transpose ----
    const int bid = blockIdx.x - PREPW_BLOCKS;
    const int n = bid >> 5, y = bid & 31;
    {
        int ch = t >> 2, x8 = (t & 3) * 8;
        const float* p = buf + ((size_t)(ch * BN + n) * LL + y * Lw + x8);
        const float* q = spa + ((size_t)(ch * BN + n) * LL + y * Lw + x8);
        float4 a0 = ((const float4*)p)[0], a1 = ((const float4*)p)[1];
        float4 b0 = ((const float4*)q)[0], b1 = ((const float4*)q)[1];
        float* d0 = &t0[ch][x8];
        float* d1 = &t1[ch][x8];
        d0[0] = a0.x; d0[1] = a0.y; d0[2] = a0.z; d0[3] = a0.w;
        d0[4] = a1.x; d0[5] = a1.y; d0[6] = a1.z; d0[7] = a1.w;
        d1[0] = a0.x + b0.x; d1[1] = a0.y + b0.y; d1[2] = a0.z + b0.z; d1[3] = a0.w + b0.w;
        d1[4] = a1.x + b1.x; d1[5] = a1.y + b1.y; d1[6] = a1.z + b1.z; d1[7] = a1.w + b1.w;
    }
    __syncthreads();
    {
        int x = t >> 3, c8 = (t & 7) * 8;
        union { ushort u[8]; uint4 v; } o0, o1;
#pragma unroll
        for (int j = 0; j < 8; j++) { o0.u[j] = f2b(t0[c8 + j][x]); o1.u[j] = f2b(t1[c8 + j][x]); }
        size_t base = (((size_t)n * Lh + y) * Lw + x) * 64 + c8;
        *(uint4*)(T + base) = o0.v;
        *(uint4*)(S + base) = o1.v;
    }
}

// ---------------------------------------------------------------------------
// Token embed + LN1 + QKV (unchanged from R8).
// ---------------------------------------------------------------------------
__global__ __launch_bounds__(256) void k_tok_qkv(
    const ushort* __restrict__ T, const ushort* __restrict__ S,
    const ushort* __restrict__ W2, const ushort* __restrict__ WQK,
    const ushort* __restrict__ WV, const float* __restrict__ g1,
    const float* __restrict__ b1, ushort* __restrict__ TOKb,
    ushort* __restrict__ Qh, ushort* __restrict__ Kh, ushort* __restrict__ VTg)
{
    const int bid = blockIdx.x;                       // 800 blocks
    const int idx = (bid & 7) * 100 + (bid >> 3);     // XCD-contiguous chunks
    const int n = idx / 32, y = idx & 31;
    __shared__ ushort At[3 * 34 * 72];
    __shared__ ushort As_[3 * 34 * 72];
    __shared__ ushort Xs[32 * 136];
    __shared__ ushort Vs[32 * 136];
    __shared__ float2 red[32][4];
    const int t = threadIdx.x;
    const uint4 z = make_uint4(0, 0, 0, 0);

    {
        int x = t >> 3, c8 = (t & 7) * 8;
#pragma unroll
        for (int dy = 0; dy < 3; dy++) {
            int yy = y + dy - 1;
            uint4 va = z, vs = z;
            if (yy >= 0 && yy < Lh) {
                size_t gi = (((size_t)n * Lh + yy) * Lw + x) * 64 + c8;
                va = *(const uint4*)(T + gi);
                vs = *(const uint4*)(S + gi);
            }
            *(uint4*)(At + (dy * 34 + x + 1) * 72 + c8) = va;
            *(uint4*)(As_ + (dy * 34 + x + 1) * 72 + c8) = vs;
        }
        if (t < 48) {
            int dy = t / 16, rem = t % 16;
            int colp = (rem >> 3) * 33, c8p = (rem & 7) * 8;
            *(uint4*)(At + (dy * 34 + colp) * 72 + c8p) = z;
            *(uint4*)(As_ + (dy * 34 + colp) * 72 + c8p) = z;
        }
    }
    __syncthreads();

    const int w = t >> 6, lane = t & 63;
    const int col = lane & 15, quad = lane >> 4;
    f32x4 accT[2][2] = {}, accS[2][2] = {};

    for (int tap = 0; tap < 9; tap++) {
        int dy = tap / 3, dx = tap % 3;
#pragma unroll
        for (int cc = 0; cc < 2; cc++) {
            int kg = tap * 64 + cc * 32 + quad * 8;
            short8 b0 = *(const short8*)(W2 + (size_t)(w * 32 + col) * 576 + kg);
            short8 bq = *(const short8*)(W2 + (size_t)(w * 32 + 16 + col) * 576 + kg);
            int abase = (dy * 34 + col + dx) * 72 + cc * 32 + quad * 8;
            short8 aT0 = *(const short8*)(At + abase);
            short8 aT1 = *(const short8*)(At + abase + 16 * 72);
            short8 aS0 = *(const short8*)(As_ + abase);
            short8 aS1 = *(const short8*)(As_ + abase + 16 * 72);
            accT[0][0] = __builtin_amdgcn_mfma_f32_16x16x32_bf16(aT0, b0, accT[0][0], 0, 0, 0);
            accT[0][1] = __builtin_amdgcn_mfma_f32_16x16x32_bf16(aT0, bq, accT[0][1], 0, 0, 0);
            accT[1][0] = __builtin_amdgcn_mfma_f32_16x16x32_bf16(aT1, b0, accT[1][0], 0, 0, 0);
            accT[1][1] = __builtin_amdgcn_mfma_f32_16x16x32_bf16(aT1, bq, accT[1][1], 0, 0, 0);
            accS[0][0] = __builtin_amdgcn_mfma_f32_16x16x32_bf16(aS0, b0, accS[0][0], 0, 0, 0);
            accS[0][1] = __builtin_amdgcn_mfma_f32_16x16x32_bf16(aS0, bq, accS[0][1], 0, 0, 0);
            accS[1][0] = __builtin_amdgcn_mfma_f32_16x16x32_bf16(aS1, b0, accS[1][0], 0, 0, 0);
            accS[1][1] = __builtin_amdgcn_mfma_f32_16x16x32_bf16(aS1, bq, accS[1][1], 0, 0, 0);
        }
    }

    // LN1 partial sums
#pragma unroll
    for (int mi = 0; mi < 2; mi++)
#pragma unroll
        for (int r = 0; r < 4; r++) {
            float a0 = accS[mi][0][r], a1 = accS[mi][1][r];
            float ss = a0 + a1, qq = a0 * a0 + a1 * a1;
#pragma unroll
            for (int m = 1; m < 16; m <<= 1) {
                ss += __shfl_xor(ss, m, 64);
                qq += __shfl_xor(qq, m, 64);
            }
            if (col == 0) red[mi * 16 + quad * 4 + r][w] = make_float2(ss, qq);
        }
    __syncthreads();

    const float ga = g1[w * 32 + col],      ba = b1[w * 32 + col];
    const float gb = g1[w * 32 + 16 + col], bb = b1[w * 32 + 16 + col];
#pragma unroll
    for (int mi = 0; mi < 2; mi++)
#pragma unroll
        for (int r = 0; r < 4; r++) {
            int x = mi * 16 + quad * 4 + r;
            float2 p0 = red[x][0], p1 = red[x][1], p2 = red[x][2], p3 = red[x][3];
            float mean = (p0.x + p1.x + p2.x + p3.x) * (1.f / 128.f);
            float var  = (p0.y + p1.y + p2.y + p3.y) * (1.f / 128.f) - mean * mean;
            float rstd = rsqrtf(var + 1e-5f);
            int e0 = w * 32 + col, e1 = w * 32 + 16 + col;
            Xs[x * 136 + e0] = f2b((accS[mi][0][r] - mean) * rstd * ga + ba);
            Xs[x * 136 + e1] = f2b((accS[mi][1][r] - mean) * rstd * gb + bb);
            Vs[x * 136 + e0] = f2b(accT[mi][0][r]);
            Vs[x * 136 + e1] = f2b(accT[mi][1][r]);
        }
    __syncthreads();

    short8 xb[2][4], xv[2][4];
#pragma unroll
    for (int j = 0; j < 2; j++)
#pragma unroll
        for (int kc = 0; kc < 4; kc++) {
            xb[j][kc] = *(const short8*)(Xs + (j * 16 + col) * 136 + kc * 32 + quad * 8);
            xv[j][kc] = *(const short8*)(Vs + (j * 16 + col) * 136 + kc * 32 + quad * 8);
        }
    f32x4 Q[2][2] = {}, K[2][2] = {}, V[2][2] = {};
#pragma unroll
    for (int hj = 0; hj < 2; hj++) {
        int h = 2 * w + hj;
#pragma unroll
        for (int kc = 0; kc < 4; kc++) {
            short8 aq = *(const short8*)(WQK + (size_t)(h * 16 + col) * 128 + kc * 32 + quad * 8);
            short8 ak = *(const short8*)(WQK + (size_t)(128 + h * 16 + col) * 128 + kc * 32 + quad * 8);
            short8 av = *(const short8*)(WV + (size_t)(h * 16 + col) * 128 + kc * 32 + quad * 8);
#pragma unroll
            for (int j = 0; j < 2; j++) {
                Q[hj][j] = __builtin_amdgcn_mfma_f32_16x16x32_bf16(aq, xb[j][kc], Q[hj][j], 0, 0, 0);
                K[hj][j] = __builtin_amdgcn_mfma_f32_16x16x32_bf16(ak, xb[j][kc], K[hj][j], 0, 0, 0);
                V[hj][j] = __builtin_amdgcn_mfma_f32_16x16x32_bf16(av, xv[j][kc], V[hj][j], 0, 0, 0);
            }
        }
    }
    ushort* VTs = At;   // [8 heads][16 d][stride 34]
#pragma unroll
    for (int hj = 0; hj < 2; hj++) {
        int h = 2 * w + hj;
#pragma unroll
        for (int j = 0; j < 2; j++) {
            int l = y * 32 + j * 16 + col;
            size_t base = ((size_t)(n * 8 + h) * 1024 + l) * 16 + quad * 4;
            ushort4 oq, ok;
            oq.x = f2b(Q[hj][j][0]); oq.y = f2b(Q[hj][j][1]); oq.z = f2b(Q[hj][j][2]); oq.w = f2b(Q[hj][j][3]);
            ok.x = f2b(K[hj][j][0]); ok.y = f2b(K[hj][j][1]); ok.z = f2b(K[hj][j][2]); ok.w = f2b(K[hj][j][3]);
            *(ushort4*)(Qh + base) = oq;
            *(ushort4*)(Kh + base) = ok;
            int xp = ((col >> 2) << 3) + (j << 2) + (col & 3);
#pragma unroll
            for (int r = 0; r < 4; r++)
                VTs[(h * 16 + quad * 4 + r) * 34 + xp] = f2b(V[hj][j][r]);
        }
    }
#pragma unroll
    for (int k = 0; k < 2; k++) {
        int idx2 = t + k * 256;
        int r = idx2 >> 4, seg = idx2 & 15;
        *(uint4*)(TOKb + ((size_t)((y * 32 + r) * 25 + n)) * 128 + seg * 8) =
            *(const uint4*)(Vs + r * 136 + seg * 8);
    }
    __syncthreads();
    {   // coalesced VTg write
        int h = t >> 5, rem = t & 31, d = rem >> 1, xh = (rem & 1) * 16;
        size_t vrow = ((size_t)(n * 8 + h) * 32 + y) * 512;
        union { ushort u[8]; uint4 v; } o0, o1;
#pragma unroll
        for (int j = 0; j < 8; j++) {
            o0.u[j] = VTs[(h * 16 + d) * 34 + xh + j];
            o1.u[j] = VTs[(h * 16 + d) * 34 + xh + 8 + j];
        }
        *(uint4*)(VTg + vrow + d * 32 + xh)     = o0.v;
        *(uint4*)(VTg + vrow + d * 32 + xh + 8) = o1.v;
    }
}

// ---------------------------------------------------------------------------
// Pure attention. Grid 1600 (n,y,half), ZERO LDS. Wave w = heads {2w,2w+1}.
// Mask hoisted to a 40-bit register mask (head-independent). 1/sum applied
// to the PV accumulator (8 muls) instead of 80 P-elements. Output AOp is the
// out_proj B-operand pack: AOp[n][l][kslot], kslot = w*32+quad*8+i,
// head = 2w+(i>>2), d = quad*4+(i&3)  — matches WOP's k-permutation.
// ---------------------------------------------------------------------------
__global__ __launch_bounds__(256) void k_attn(
    const ushort* __restrict__ Qh, const ushort* __restrict__ Kh,
    const ushort* __restrict__ VTg, ushort* __restrict__ AOp)
{
    const int bid = blockIdx.x;                       // 1600 blocks
    const int idx = (bid & 7) * 200 + (bid >> 3);     // XCD-contiguous chunks
    const int n = idx / 64, rem = idx & 63;
    const int y = rem >> 1, half = rem & 1;
    const int t = threadIdx.x, w = t >> 6, lane = t & 63;
    const int col = lane & 15, quad = lane >> 4;
    const int qx = half * 16 + col;

    // hoisted mask bits (valid slot (tt,r) for this lane's quad)
    unsigned long long mbits = 0;
#pragma unroll
    for (int tt = 0; tt < 10; tt++) {
        int yy = y - 2 + (tt >> 1);
        bool rok = (yy >= 0) && (yy < 32);
        int kxb = ((tt & 1) << 4) + quad * 4;
#pragma unroll
        for (int r = 0; r < 4; r++) {
            int dd = kxb + r - qx;
            if (rok && ((unsigned)(dd + 2) <= 4u))
                mbits |= 1ull << (tt * 4 + r);
        }
    }

    short8 z8 = {0, 0, 0, 0, 0, 0, 0, 0};
    f32x4 O2[2] = {};
#pragma unroll
    for (int hj = 0; hj < 2; hj++) {
        const int h = 2 * w + hj;
        const size_t base = (size_t)(n * 8 + h) * 1024;
        const size_t vbase = ((size_t)(n * 8 + h) * 32) * 512;

        short8 qf = z8;
        if (quad < 2)
            qf = *(const short8*)(Qh + (base + y * 32 + half * 16 + col) * 16 + quad * 8);

        f32x4 Sc[10] = {};
#pragma unroll
        for (int tt = 0; tt < 10; tt++) {
            int kr = tt >> 1, kx = ((tt & 1) << 4) + col;
            int yyc = min(max(y - 2 + kr, 0), 31);
            short8 kf = z8;
            if (quad < 2)
                kf = *(const short8*)(Kh + (base + yyc * 32 + kx) * 16 + quad * 8);
            Sc[tt] = __builtin_amdgcn_mfma_f32_16x16x32_bf16(kf, qf, Sc[tt], 0, 0, 0);
        }

        float mx = -1e30f;
#pragma unroll
        for (int tt = 0; tt < 10; tt++)
#pragma unroll
            for (int r = 0; r < 4; r++) {
                bool ok = (mbits >> (tt * 4 + r)) & 1;
                float v = ok ? Sc[tt][r] : -1e30f;
                Sc[tt][r] = v;
                mx = fmaxf(mx, v);
            }
        mx = fmaxf(mx, __shfl_xor(mx, 16, 64));
        mx = fmaxf(mx, __shfl_xor(mx, 32, 64));
        float sum = 0.f;
#pragma unroll
        for (int tt = 0; tt < 10; tt++)
#pragma unroll
            for (int r = 0; r < 4; r++) {
                float p = __expf(Sc[tt][r] - mx);
                Sc[tt][r] = p;
                sum += p;
            }
        sum += __shfl_xor(sum, 16, 64);
        sum += __shfl_xor(sum, 32, 64);
        const float inv = 1.f / sum;

        // PV: A-frags directly from VTg; P packed UNNORMALIZED
#pragma unroll
        for (int c = 0; c < 5; c++) {
            int yyc = min(max(y - 2 + c, 0), 31);
            short8 vt = *(const short8*)(VTg + vbase + (size_t)yyc * 512 + col * 32 + quad * 8);
            union { ushort u[8]; short8 s; } pb;
#pragma unroll
            for (int i = 0; i < 8; i++)
                pb.u[i] = f2b(Sc[2 * c + (i >> 2)][i & 3]);
            O2[hj] = __builtin_amdgcn_mfma_f32_16x16x32_bf16(vt, pb.s, O2[hj], 0, 0, 0);
        }
        // normalize once (4 muls/head)
#pragma unroll
        for (int r = 0; r < 4; r++) O2[hj][r] *= inv;
    }

    // pack & store (B-operand order); per wave: 16 rows x 64B lines
    union { ushort u[8]; uint4 v; } pb;
#pragma unroll
    for (int i = 0; i < 8; i++)
        pb.u[i] = f2b(O2[i >> 2][i & 3]);
    *(uint4*)(AOp + ((size_t)(n * 1024 + y * 32 + half * 16 + col)) * 128 + w * 32 + quad * 8) = pb.v;
}

// ---------------------------------------------------------------------------
// out_proj + residual + LN2 + FFN + conv. Grid 1600 (same swizzle as k_attn
// -> AOp is XCD-L2-local). B-frags for out_proj read directly from AOp.
// ---------------------------------------------------------------------------
__global__ __launch_bounds__(256) void k_oln_ffn(
    const ushort* __restrict__ AOp, const ushort* __restrict__ WOP,
    const float* __restrict__ g2, const float* __restrict__ b2,
    const ushort* __restrict__ W1, const ushort* __restrict__ W2P,
    const ushort* __restrict__ WCP, const ushort* __restrict__ TOKb,
    float* __restrict__ out)
{
    __shared__ ushort OX[16 * 136];
    __shared__ ushort Rs[16 * 136];
    __shared__ ushort Hs[16 * 264];
    __shared__ ushort Ys[16 * 136];
    __shared__ float2 red[16][4];
    const int bid = blockIdx.x;                       // 1600 blocks
    const int idx = (bid & 7) * 200 + (bid >> 3);
    const int n = idx / 64, rem = idx & 63;
    const int y = rem >> 1, half = rem & 1;
    const int l0 = y * 32 + half * 16;
    const int t = threadIdx.x, w = t >> 6, lane = t & 63;
    const int col = lane & 15, quad = lane >> 4;

    {   // stage residual rows (16 tokens, bf16)
        int r = t >> 4, seg = t & 15;
        *(uint4*)(Rs + r * 136 + seg * 8) =
            *(const uint4*)(TOKb + ((size_t)((l0 + r) * 25 + n)) * 128 + seg * 8);
    }
    __syncthreads();

    // out_proj: B-frags straight from AOp; wave w -> e-tiles {2w, 2w+1}
    f32x4 Y[2] = {};
#pragma unroll
    for (int kc = 0; kc < 4; kc++) {
        short8 hb = *(const short8*)(AOp + ((size_t)(n * 1024 + l0 + col)) * 128 + kc * 32 + quad * 8);
#pragma unroll
        for (int jj = 0; jj < 2; jj++) {
            int et = 2 * w + jj;
            short8 a = *(const short8*)(WOP + (size_t)(et * 16 + col) * 128 + kc * 32 + quad * 8);
            Y[jj] = __builtin_amdgcn_mfma_f32_16x16x32_bf16(a, hb, Y[jj], 0, 0, 0);
        }
    }
    // residual + LN2 stats (token = col); tok2 stays in Y[] registers
    float sum = 0.f, sq = 0.f;
#pragma unroll
    for (int jj = 0; jj < 2; jj++)
#pragma unroll
        for (int r = 0; r < 4; r++) {
            int e = (2 * w + jj) * 16 + quad * 4 + r;
            float v = Y[jj][r] + b2f(Rs[col * 136 + e]);
            Y[jj][r] = v;
            sum += v; sq += v * v;
        }
    sum += __shfl_xor(sum, 16, 64); sum += __shfl_xor(sum, 32, 64);
    sq  += __shfl_xor(sq, 16, 64);  sq  += __shfl_xor(sq, 32, 64);
    if (quad == 0) red[col][w] = make_float2(sum, sq);
    __syncthreads();

    {
        float2 p0 = red[col][0], p1 = red[col][1], p2 = red[col][2], p3 = red[col][3];
        float mean = (p0.x + p1.x + p2.x + p3.x) * (1.f / 128.f);
        float var  = (p0.y + p1.y + p2.y + p3.y) * (1.f / 128.f) - mean * mean;
        float rstd = rsqrtf(var + 1e-5f);
#pragma unroll
        for (int jj = 0; jj < 2; jj++)
#pragma unroll
            for (int r = 0; r < 4; r++) {
                int e = (2 * w + jj) * 16 + quad * 4 + r;
                OX[col * 136 + e] = f2b((Y[jj][r] - mean) * rstd * g2[e] + b2[e]);
            }
    }
    __syncthreads();

    // ffn phase 1
    short8 xb[4];
#pragma unroll
    for (int kc = 0; kc < 4; kc++)
        xb[kc] = *(const short8*)(OX + col * 136 + kc * 32 + quad * 8);
    f32x4 H[4] = {};
#pragma unroll
    for (int j = 0; j < 4; j++) {
        int ft = 4 * w + j;
#pragma unroll
        for (int kc = 0; kc < 4; kc++) {
            short8 a = *(const short8*)(W1 + (size_t)(ft * 16 + col) * 128 + kc * 32 + quad * 8);
            H[j] = __builtin_amdgcn_mfma_f32_16x16x32_bf16(a, xb[kc], H[j], 0, 0, 0);
        }
    }
#pragma unroll
    for (int cc = 0; cc < 2; cc++) {
        union { ushort u[8]; uint4 v; } pb;
#pragma unroll
        for (int i = 0; i < 8; i++)
            pb.u[i] = f2b(fmaxf(H[2 * cc + (i >> 2)][i & 3], 0.f));
        *(uint4*)(Hs + col * 264 + (2 * w + cc) * 32 + quad * 8) = pb.v;
    }
    __syncthreads();

    // ffn phase 2; residual from Y[] registers
    f32x4 Y2[2] = {};
#pragma unroll
    for (int kc = 0; kc < 8; kc++) {
        short8 hb = *(const short8*)(Hs + col * 264 + kc * 32 + quad * 8);
#pragma unroll
        for (int j = 0; j < 2; j++) {
            int et = 2 * w + j;
            short8 a = *(const short8*)(W2P + (size_t)(et * 16 + col) * 256 + kc * 32 + quad * 8);
            Y2[j] = __builtin_amdgcn_mfma_f32_16x16x32_bf16(a, hb, Y2[j], 0, 0, 0);
        }
    }
    {
        union { ushort u[8]; uint4 v; } pb;
#pragma unroll
        for (int i = 0; i < 8; i++)
            pb.u[i] = f2b(Y2[i >> 2][i & 3] + Y[i >> 2][i & 3]);
        *(uint4*)(Ys + col * 136 + w * 32 + quad * 8) = pb.v;
    }
    __syncthreads();

    // conv, ot = w
    f32x4 O = {};
#pragma unroll
    for (int c = 0; c < 4; c++) {
        short8 yb = *(const short8*)(Ys + col * 136 + c * 32 + quad * 8);
        short8 a = *(const short8*)(WCP + (size_t)(w * 16 + col) * 128 + c * 32 + quad * 8);
        O = __builtin_amdgcn_mfma_f32_16x16x32_bf16(a, yb, O, 0, 0, 0);
    }
    const int l = l0 + col;
#pragma unroll
    for (int r2 = 0; r2 < 4; r2++) {
        int o = w * 16 + quad * 4 + r2;
        out[(size_t)(o * 25 + n) * 1024 + l] = O[r2];
    }
}

// ---------------------------------------------------------------------------
// Launch
// ---------------------------------------------------------------------------
extern "C" void kernel_launch(void* const* d_in, const int* in_sizes, int n_in,
                              void* d_out, int out_size, void* d_ws, size_t ws_size,
                              hipStream_t stream)
{
    const float* buffer   = (const float*)d_in[0];
    const float* spa      = (const float*)d_in[1];
    const float* w_mlp    = (const float*)d_in[2];
    const float* ln1_g    = (const float*)d_in[3];
    const float* ln1_b    = (const float*)d_in[4];
    const float* in_proj  = (const float*)d_in[5];
    const float* out_proj = (const float*)d_in[6];
    const float* ln2_g    = (const float*)d_in[7];
    const float* ln2_b    = (const float*)d_in[8];
    const float* ff_w1    = (const float*)d_in[9];
    const float* ff_w2    = (const float*)d_in[10];
    const float* conv_w   = (const float*)d_in[11];
    float* out = (float*)d_out;

    char* ws = (char*)d_ws;
    ushort* TOKb = (ushort*)(ws);                //  6,553,600 residual bf16
    ushort* Qh   = (ushort*)(ws + 6553600);      //  6,553,600 [n][h][l][d]
    ushort* Kh   = (ushort*)(ws + 13107200);     //  6,553,600
    ushort* VTg  = (ushort*)(ws + 19660800);     //  6,553,600 [n][h][y][d][xp]
    ushort* AOp  = (ushort*)(ws + 26214400);     //  6,553,600 [n][l][kslot]
    ushort* Tbf  = (ushort*)(ws + 32768000);     //  3,276,800
    ushort* Sbf  = (ushort*)(ws + 36044800);     //  3,276,800
    ushort* Wb   = (ushort*)(ws + 39321600);     //    425,984

    k_prep<<<dim3(PREPW_BLOCKS + 800), 256, 0, stream>>>(
        w_mlp, in_proj, out_proj, ff_w1, ff_w2, conv_w,
        buffer, spa, Wb, Tbf, Sbf);
    k_tok_qkv<<<dim3(800), 256, 0, stream>>>(Tbf, Sbf, Wb + OFF_W2,
                                             Wb + OFF_WQK, Wb + OFF_WV,
                                             ln1_g, ln1_b, TOKb, Qh, Kh, VTg);
    k_attn<<<dim3(1600), 256, 0, stream>>>(Qh, Kh, VTg, AOp);
    k_oln_ffn<<<dim3(1600), 256, 0, stream>>>(AOp, Wb + OFF_WO, ln2_g, ln2_b,
                                              Wb + OFF_W1, Wb + OFF_W2F,
                                              Wb + OFF_WC, TOKb, out);
}

// Round 10
// 174.461 us; speedup vs baseline: 1.0532x; 1.0532x over previous
//
#include <hip/hip_runtime.h>
#include <math.h>

// SpaTrans on MI355X. R10: R8 structure (best-known 176us) minus the T/S
// round-trip: input transpose fused into k_tok_qkv (transpose scratch
// aliased onto Xs/Vs LDS). k_prep is weights-only. k_attn_ffn gains R9's
// verified micro-opts (hoisted mask bitmask, deferred 1/sum).
#define Lh 32
#define Lw 32
#define LL 1024
#define BN 25
#define EE 128
#define CC 64
#define NHD 8
#define DH 16
#define FFD 256
#define MROWS 25600

typedef __attribute__((ext_vector_type(8))) short short8;
typedef __attribute__((ext_vector_type(4))) float f32x4;

__device__ inline ushort f2b(float x) {
    union { float f; unsigned u; } v; v.f = x;
    unsigned r = (v.u + 0x7fffu + ((v.u >> 16) & 1u)) >> 16;
    return (ushort)r;
}
__device__ inline float b2f(ushort u) {
    union { unsigned u; float f; } v; v.u = ((unsigned)u) << 16;
    return v.f;
}

// ---------------------------------------------------------------------------
// Weight layout (ushorts). W2 K-reordered (k'=tap*64+ch). WO/W2F/WC k-PERMUTED
// (kpos=c*32+q*8+i <-> orig k=(2c+(i>>2))*16+q*4+(i&3)). Q rows pre-scaled 0.25.
// ---------------------------------------------------------------------------
#define OFF_W2  0
#define OFF_WQK 73728
#define OFF_WV  106496
#define OFF_WO  122880
#define OFF_W1  139264
#define OFF_W2F 172032
#define OFF_WC  204800
#define W_TOTAL 212992

__global__ __launch_bounds__(256) void k_prep(
    const float* __restrict__ w_mlp, const float* __restrict__ in_proj,
    const float* __restrict__ out_proj, const float* __restrict__ ff_w1,
    const float* __restrict__ ff_w2, const float* __restrict__ conv_w,
    ushort* __restrict__ Wb)
{
    int i = blockIdx.x * 256 + threadIdx.x;
    if (i >= W_TOTAL) return;
    if (i < 73728) {
        int e = i / 576, k = i - e * 576;
        int tap = k >> 6, ch = k & 63;
        Wb[OFF_W2 + i] = f2b(w_mlp[e * 576 + ch * 9 + tap]);
        return;
    }
    i -= 73728;
    if (i < 32768) {   // WQK; Q rows pre-scaled by 1/sqrt(16)
        float v = in_proj[i];
        Wb[OFF_WQK + i] = f2b(i < 16384 ? v * 0.25f : v);
        return;
    }
    i -= 32768;
    if (i < 16384) { Wb[OFF_WV + i] = f2b(in_proj[32768 + i]); return; }
    i -= 16384;
    if (i < 16384) {   // WO, k-permuted (K=128)
        int e = i >> 7, kpos = i & 127;
        int c = kpos >> 5, q = (kpos >> 3) & 3, ii = kpos & 7;
        int orig = (2 * c + (ii >> 2)) * 16 + q * 4 + (ii & 3);
        Wb[OFF_WO + i] = f2b(out_proj[e * 128 + orig]);
        return;
    }
    i -= 16384;
    if (i < 32768) { Wb[OFF_W1 + i] = f2b(ff_w1[i]); return; }
    i -= 32768;
    if (i < 32768) {   // W2F, k-permuted (K=256)
        int e = i >> 8, kpos = i & 255;
        int c = kpos >> 5, q = (kpos >> 3) & 3, ii = kpos & 7;
        int orig = (2 * c + (ii >> 2)) * 16 + q * 4 + (ii & 3);
        Wb[OFF_W2F + i] = f2b(ff_w2[e * 256 + orig]);
        return;
    }
    i -= 32768;
    {                  // WC, k-permuted (K=128)
        int o = i >> 7, kpos = i & 127;
        int c = kpos >> 5, q = (kpos >> 3) & 3, ii = kpos & 7;
        int orig = (2 * c + (ii >> 2)) * 16 + q * 4 + (ii & 3);
        Wb[OFF_WC + i] = f2b(conv_w[o * 128 + orig]);
    }
}

// ---------------------------------------------------------------------------
// Token embed + LN1 + QKV, with INPUT TRANSPOSE FUSED. Grid 800, XCD-swizzled
// -> (n, y). Per row dy: stage fp32 buf/spa (t0/t1 aliased on Xs/Vs), LDS
// transpose -> At/As_ bf16 [x][ch] (stride 72). Then as R8.
// ---------------------------------------------------------------------------
__global__ __launch_bounds__(256) void k_tok_qkv(
    const float* __restrict__ buf, const float* __restrict__ spa,
    const ushort* __restrict__ W2, const ushort* __restrict__ WQK,
    const ushort* __restrict__ WV, const float* __restrict__ g1,
    const float* __restrict__ b1, ushort* __restrict__ TOKb,
    ushort* __restrict__ Qh, ushort* __restrict__ Kh, ushort* __restrict__ VTg)
{
    const int bid = blockIdx.x;                       // 800 blocks
    const int idx = (bid & 7) * 100 + (bid >> 3);     // XCD-contiguous chunks
    const int n = idx / 32, y = idx & 31;
    __shared__ ushort At[3 * 34 * 72];
    __shared__ ushort As_[3 * 34 * 72];
    __shared__ ushort Xs[32 * 136];   // phase A: aliased as t0 (fp32 [64][33])
    __shared__ ushort Vs[32 * 136];   // phase A: aliased as t1
    __shared__ float2 red[32][4];
    float* t0 = (float*)Xs;
    float* t1 = (float*)Vs;
    const int t = threadIdx.x;
    const uint4 z = make_uint4(0, 0, 0, 0);

    // ---- fused input transpose: 3 rows (y-1, y, y+1) ----
    for (int dy = 0; dy < 3; dy++) {
        int yy = y + dy - 1;
        if (yy >= 0 && yy < Lh) {
            {   // stage fp32: ch = t>>2, 8 x's per thread
                int ch = t >> 2, x8 = (t & 3) * 8;
                const float* p = buf + ((size_t)(ch * BN + n) * LL + yy * Lw + x8);
                const float* q = spa + ((size_t)(ch * BN + n) * LL + yy * Lw + x8);
                float4 a0 = ((const float4*)p)[0], a1 = ((const float4*)p)[1];
                float4 b0 = ((const float4*)q)[0], b1 = ((const float4*)q)[1];
                float* d0 = t0 + ch * 33 + x8;
                float* d1 = t1 + ch * 33 + x8;
                d0[0] = a0.x; d0[1] = a0.y; d0[2] = a0.z; d0[3] = a0.w;
                d0[4] = a1.x; d0[5] = a1.y; d0[6] = a1.z; d0[7] = a1.w;
                d1[0] = a0.x + b0.x; d1[1] = a0.y + b0.y; d1[2] = a0.z + b0.z; d1[3] = a0.w + b0.w;
                d1[4] = a1.x + b1.x; d1[5] = a1.y + b1.y; d1[6] = a1.z + b1.z; d1[7] = a1.w + b1.w;
            }
            __syncthreads();
            {   // transpose -> At/As_ bf16, vectorized b128 writes
                int x = t >> 3, c8 = (t & 7) * 8;
                union { ushort u[8]; uint4 v; } o0, o1;
#pragma unroll
                for (int j = 0; j < 8; j++) {
                    o0.u[j] = f2b(t0[(c8 + j) * 33 + x]);
                    o1.u[j] = f2b(t1[(c8 + j) * 33 + x]);
                }
                *(uint4*)(At + (dy * 34 + x + 1) * 72 + c8) = o0.v;
                *(uint4*)(As_ + (dy * 34 + x + 1) * 72 + c8) = o1.v;
            }
            __syncthreads();   // protect t0/t1 reuse next dy
        } else {
            int x = t >> 3, c8 = (t & 7) * 8;
            *(uint4*)(At + (dy * 34 + x + 1) * 72 + c8) = z;
            *(uint4*)(As_ + (dy * 34 + x + 1) * 72 + c8) = z;
        }
    }
    if (t < 48) {   // zero pad columns (x=-1 and x=32)
        int dy = t / 16, rem = t % 16;
        int colp = (rem >> 3) * 33, c8p = (rem & 7) * 8;
        *(uint4*)(At + (dy * 34 + colp) * 72 + c8p) = z;
        *(uint4*)(As_ + (dy * 34 + colp) * 72 + c8p) = z;
    }
    __syncthreads();

    const int w = t >> 6, lane = t & 63;
    const int col = lane & 15, quad = lane >> 4;
    f32x4 accT[2][2] = {}, accS[2][2] = {};

    for (int tap = 0; tap < 9; tap++) {
        int dy = tap / 3, dx = tap % 3;
#pragma unroll
        for (int cc = 0; cc < 2; cc++) {
            int kg = tap * 64 + cc * 32 + quad * 8;
            short8 b0 = *(const short8*)(W2 + (size_t)(w * 32 + col) * 576 + kg);
            short8 bq = *(const short8*)(W2 + (size_t)(w * 32 + 16 + col) * 576 + kg);
            int abase = (dy * 34 + col + dx) * 72 + cc * 32 + quad * 8;
            short8 aT0 = *(const short8*)(At + abase);
            short8 aT1 = *(const short8*)(At + abase + 16 * 72);
            short8 aS0 = *(const short8*)(As_ + abase);
            short8 aS1 = *(const short8*)(As_ + abase + 16 * 72);
            accT[0][0] = __builtin_amdgcn_mfma_f32_16x16x32_bf16(aT0, b0, accT[0][0], 0, 0, 0);
            accT[0][1] = __builtin_amdgcn_mfma_f32_16x16x32_bf16(aT0, bq, accT[0][1], 0, 0, 0);
            accT[1][0] = __builtin_amdgcn_mfma_f32_16x16x32_bf16(aT1, b0, accT[1][0], 0, 0, 0);
            accT[1][1] = __builtin_amdgcn_mfma_f32_16x16x32_bf16(aT1, bq, accT[1][1], 0, 0, 0);
            accS[0][0] = __builtin_amdgcn_mfma_f32_16x16x32_bf16(aS0, b0, accS[0][0], 0, 0, 0);
            accS[0][1] = __builtin_amdgcn_mfma_f32_16x16x32_bf16(aS0, bq, accS[0][1], 0, 0, 0);
            accS[1][0] = __builtin_amdgcn_mfma_f32_16x16x32_bf16(aS1, b0, accS[1][0], 0, 0, 0);
            accS[1][1] = __builtin_amdgcn_mfma_f32_16x16x32_bf16(aS1, bq, accS[1][1], 0, 0, 0);
        }
    }

    // LN1 partial sums
#pragma unroll
    for (int mi = 0; mi < 2; mi++)
#pragma unroll
        for (int r = 0; r < 4; r++) {
            float a0 = accS[mi][0][r], a1 = accS[mi][1][r];
            float ss = a0 + a1, qq = a0 * a0 + a1 * a1;
#pragma unroll
            for (int m = 1; m < 16; m <<= 1) {
                ss += __shfl_xor(ss, m, 64);
                qq += __shfl_xor(qq, m, 64);
            }
            if (col == 0) red[mi * 16 + quad * 4 + r][w] = make_float2(ss, qq);
        }
    __syncthreads();

    const float ga = g1[w * 32 + col],      ba = b1[w * 32 + col];
    const float gb = g1[w * 32 + 16 + col], bb = b1[w * 32 + 16 + col];
#pragma unroll
    for (int mi = 0; mi < 2; mi++)
#pragma unroll
        for (int r = 0; r < 4; r++) {
            int x = mi * 16 + quad * 4 + r;
            float2 p0 = red[x][0], p1 = red[x][1], p2 = red[x][2], p3 = red[x][3];
            float mean = (p0.x + p1.x + p2.x + p3.x) * (1.f / 128.f);
            float var  = (p0.y + p1.y + p2.y + p3.y) * (1.f / 128.f) - mean * mean;
            float rstd = rsqrtf(var + 1e-5f);
            int e0 = w * 32 + col, e1 = w * 32 + 16 + col;
            Xs[x * 136 + e0] = f2b((accS[mi][0][r] - mean) * rstd * ga + ba);
            Xs[x * 136 + e1] = f2b((accS[mi][1][r] - mean) * rstd * gb + bb);
            Vs[x * 136 + e0] = f2b(accT[mi][0][r]);
            Vs[x * 136 + e1] = f2b(accT[mi][1][r]);
        }
    __syncthreads();

    // phase B: QKV. Wave w -> heads 2w, 2w+1; token tiles j=0,1.
    short8 xb[2][4], xv[2][4];
#pragma unroll
    for (int j = 0; j < 2; j++)
#pragma unroll
        for (int kc = 0; kc < 4; kc++) {
            xb[j][kc] = *(const short8*)(Xs + (j * 16 + col) * 136 + kc * 32 + quad * 8);
            xv[j][kc] = *(const short8*)(Vs + (j * 16 + col) * 136 + kc * 32 + quad * 8);
        }
    f32x4 Q[2][2] = {}, K[2][2] = {}, V[2][2] = {};
#pragma unroll
    for (int hj = 0; hj < 2; hj++) {
        int h = 2 * w + hj;
#pragma unroll
        for (int kc = 0; kc < 4; kc++) {
            short8 aq = *(const short8*)(WQK + (size_t)(h * 16 + col) * 128 + kc * 32 + quad * 8);
            short8 ak = *(const short8*)(WQK + (size_t)(128 + h * 16 + col) * 128 + kc * 32 + quad * 8);
            short8 av = *(const short8*)(WV + (size_t)(h * 16 + col) * 128 + kc * 32 + quad * 8);
#pragma unroll
            for (int j = 0; j < 2; j++) {
                Q[hj][j] = __builtin_amdgcn_mfma_f32_16x16x32_bf16(aq, xb[j][kc], Q[hj][j], 0, 0, 0);
                K[hj][j] = __builtin_amdgcn_mfma_f32_16x16x32_bf16(ak, xb[j][kc], K[hj][j], 0, 0, 0);
                V[hj][j] = __builtin_amdgcn_mfma_f32_16x16x32_bf16(av, xv[j][kc], V[hj][j], 0, 0, 0);
            }
        }
    }
    ushort* VTs = At;   // dead after MFMA loop; [8 heads][16 d][stride 34]
#pragma unroll
    for (int hj = 0; hj < 2; hj++) {
        int h = 2 * w + hj;
#pragma unroll
        for (int j = 0; j < 2; j++) {
            int l = y * 32 + j * 16 + col;
            size_t base = ((size_t)(n * 8 + h) * 1024 + l) * 16 + quad * 4;
            ushort4 oq, ok;
            oq.x = f2b(Q[hj][j][0]); oq.y = f2b(Q[hj][j][1]); oq.z = f2b(Q[hj][j][2]); oq.w = f2b(Q[hj][j][3]);
            ok.x = f2b(K[hj][j][0]); ok.y = f2b(K[hj][j][1]); ok.z = f2b(K[hj][j][2]); ok.w = f2b(K[hj][j][3]);
            *(ushort4*)(Qh + base) = oq;
            *(ushort4*)(Kh + base) = ok;
            int xp = ((col >> 2) << 3) + (j << 2) + (col & 3);
#pragma unroll
            for (int r = 0; r < 4; r++)
                VTs[(h * 16 + quad * 4 + r) * 34 + xp] = f2b(V[hj][j][r]);
        }
    }
#pragma unroll
    for (int k = 0; k < 2; k++) {
        int idx2 = t + k * 256;
        int r = idx2 >> 4, seg = idx2 & 15;
        *(uint4*)(TOKb + ((size_t)((y * 32 + r) * 25 + n)) * 128 + seg * 8) =
            *(const uint4*)(Vs + r * 136 + seg * 8);
    }
    __syncthreads();
    {   // coalesced VTg write
        int h = t >> 5, rem = t & 31, d = rem >> 1, xh = (rem & 1) * 16;
        size_t vrow = ((size_t)(n * 8 + h) * 32 + y) * 512;
        union { ushort u[8]; uint4 v; } o0, o1;
#pragma unroll
        for (int j = 0; j < 8; j++) {
            o0.u[j] = VTs[(h * 16 + d) * 34 + xh + j];
            o1.u[j] = VTs[(h * 16 + d) * 34 + xh + 8 + j];
        }
        *(uint4*)(VTg + vrow + d * 32 + xh)     = o0.v;
        *(uint4*)(VTg + vrow + d * 32 + xh + 8) = o1.v;
    }
}

// ---------------------------------------------------------------------------
// Attention + out_proj + residual + LN2 + FFN + conv, fully fused (R8) with
// R9 micro-opts: hoisted 40-bit mask, deferred 1/sum. Grid 1600 (n,y,half).
// ---------------------------------------------------------------------------
__global__ __launch_bounds__(256) void k_attn_ffn(
    const ushort* __restrict__ Qh, const ushort* __restrict__ Kh,
    const ushort* __restrict__ VTg, const ushort* __restrict__ WOP,
    const float* __restrict__ g2, const float* __restrict__ b2,
    const ushort* __restrict__ W1, const ushort* __restrict__ W2P,
    const ushort* __restrict__ WCP, const ushort* __restrict__ TOKb,
    float* __restrict__ out)
{
    __shared__ ushort OX[16 * 136];
    __shared__ ushort Rs[16 * 136];
    __shared__ ushort Hs[16 * 264];
    __shared__ ushort Ys[16 * 136];
    __shared__ float2 red[16][4];
    const int bid = blockIdx.x;                       // 1600 blocks
    const int idx = (bid & 7) * 200 + (bid >> 3);     // XCD-contiguous chunks
    const int n = idx / 64, rem = idx & 63;
    const int y = rem >> 1, half = rem & 1;
    const int l0 = y * 32 + half * 16;
    const int t = threadIdx.x, w = t >> 6, lane = t & 63;
    const int col = lane & 15, quad = lane >> 4;
    const int qx = half * 16 + col;

    {   // stage residual rows (16 tokens, bf16)
        int r = t >> 4, seg = t & 15;
        *(uint4*)(Rs + r * 136 + seg * 8) =
            *(const uint4*)(TOKb + ((size_t)((l0 + r) * 25 + n)) * 128 + seg * 8);
    }

    // hoisted mask bits (head-independent)
    unsigned long long mbits = 0;
#pragma unroll
    for (int tt = 0; tt < 10; tt++) {
        int yy = y - 2 + (tt >> 1);
        bool rok = (yy >= 0) && (yy < 32);
        int kxb = ((tt & 1) << 4) + quad * 4;
#pragma unroll
        for (int r = 0; r < 4; r++) {
            int dd = kxb + r - qx;
            if (rok && ((unsigned)(dd + 2) <= 4u))
                mbits |= 1ull << (tt * 4 + r);
        }
    }

    short8 z8 = {0, 0, 0, 0, 0, 0, 0, 0};
    f32x4 O2[2] = {};
#pragma unroll
    for (int hj = 0; hj < 2; hj++) {
        const int h = 2 * w + hj;
        const size_t base = (size_t)(n * 8 + h) * 1024;
        const size_t vbase = ((size_t)(n * 8 + h) * 32) * 512;

        short8 qf = z8;
        if (quad < 2)
            qf = *(const short8*)(Qh + (base + y * 32 + half * 16 + col) * 16 + quad * 8);

        f32x4 Sc[10] = {};
#pragma unroll
        for (int tt = 0; tt < 10; tt++) {
            int kr = tt >> 1, kx = ((tt & 1) << 4) + col;
            int yyc = min(max(y - 2 + kr, 0), 31);
            short8 kf = z8;
            if (quad < 2)
                kf = *(const short8*)(Kh + (base + yyc * 32 + kx) * 16 + quad * 8);
            Sc[tt] = __builtin_amdgcn_mfma_f32_16x16x32_bf16(kf, qf, Sc[tt], 0, 0, 0);
        }

        float mx = -1e30f;
#pragma unroll
        for (int tt = 0; tt < 10; tt++)
#pragma unroll
            for (int r = 0; r < 4; r++) {
                bool ok = (mbits >> (tt * 4 + r)) & 1;
                float v = ok ? Sc[tt][r] : -1e30f;
                Sc[tt][r] = v;
                mx = fmaxf(mx, v);
            }
        mx = fmaxf(mx, __shfl_xor(mx, 16, 64));
        mx = fmaxf(mx, __shfl_xor(mx, 32, 64));
        float sum = 0.f;
#pragma unroll
        for (int tt = 0; tt < 10; tt++)
#pragma unroll
            for (int r = 0; r < 4; r++) {
                float p = __expf(Sc[tt][r] - mx);
                Sc[tt][r] = p;
                sum += p;
            }
        sum += __shfl_xor(sum, 16, 64);
        sum += __shfl_xor(sum, 32, 64);
        const float inv = 1.f / sum;

        // PV: A-frags from VTg; P packed UNNORMALIZED, normalize O2 once
#pragma unroll
        for (int c = 0; c < 5; c++) {
            int yyc = min(max(y - 2 + c, 0), 31);
            short8 vt = *(const short8*)(VTg + vbase + (size_t)yyc * 512 + col * 32 + quad * 8);
            union { ushort u[8]; short8 s; } pb;
#pragma unroll
            for (int i = 0; i < 8; i++)
                pb.u[i] = f2b(Sc[2 * c + (i >> 2)][i & 3]);
            O2[hj] = __builtin_amdgcn_mfma_f32_16x16x32_bf16(vt, pb.s, O2[hj], 0, 0, 0);
        }
#pragma unroll
        for (int r = 0; r < 4; r++) O2[hj][r] *= inv;
    }

    // pack O (heads 2w,2w+1) -> OX as B-operand k-slice w
    {
        union { ushort u[8]; uint4 v; } pb;
#pragma unroll
        for (int i = 0; i < 8; i++)
            pb.u[i] = f2b(O2[i >> 2][i & 3]);
        *(uint4*)(OX + col * 136 + w * 32 + quad * 8) = pb.v;
    }
    __syncthreads();

    // out_proj: wave w -> e-tiles {2w, 2w+1}
    f32x4 Y[2] = {};
#pragma unroll
    for (int kc = 0; kc < 4; kc++) {
        short8 hb = *(const short8*)(OX + col * 136 + kc * 32 + quad * 8);
#pragma unroll
        for (int jj = 0; jj < 2; jj++) {
            int et = 2 * w + jj;
            short8 a = *(const short8*)(WOP + (size_t)(et * 16 + col) * 128 + kc * 32 + quad * 8);
            Y[jj] = __builtin_amdgcn_mfma_f32_16x16x32_bf16(a, hb, Y[jj], 0, 0, 0);
        }
    }
    // residual + LN2 stats (token = col); tok2 stays in Y[] registers
    float sum = 0.f, sq = 0.f;
#pragma unroll
    for (int jj = 0; jj < 2; jj++)
#pragma unroll
        for (int r = 0; r < 4; r++) {
            int e = (2 * w + jj) * 16 + quad * 4 + r;
            float v = Y[jj][r] + b2f(Rs[col * 136 + e]);
            Y[jj][r] = v;
            sum += v; sq += v * v;
        }
    sum += __shfl_xor(sum, 16, 64); sum += __shfl_xor(sum, 32, 64);
    sq  += __shfl_xor(sq, 16, 64);  sq  += __shfl_xor(sq, 32, 64);
    if (quad == 0) red[col][w] = make_float2(sum, sq);
    __syncthreads();

    {
        float2 p0 = red[col][0], p1 = red[col][1], p2 = red[col][2], p3 = red[col][3];
        float mean = (p0.x + p1.x + p2.x + p3.x) * (1.f / 128.f);
        float var  = (p0.y + p1.y + p2.y + p3.y) * (1.f / 128.f) - mean * mean;
        float rstd = rsqrtf(var + 1e-5f);
#pragma unroll
        for (int jj = 0; jj < 2; jj++)
#pragma unroll
            for (int r = 0; r < 4; r++) {
                int e = (2 * w + jj) * 16 + quad * 4 + r;
                OX[col * 136 + e] = f2b((Y[jj][r] - mean) * rstd * g2[e] + b2[e]);
            }
    }
    __syncthreads();

    // ffn phase 1: ft = 4w..4w+3 over K=128 from OX
    short8 xb[4];
#pragma unroll
    for (int kc = 0; kc < 4; kc++)
        xb[kc] = *(const short8*)(OX + col * 136 + kc * 32 + quad * 8);
    f32x4 H[4] = {};
#pragma unroll
    for (int j = 0; j < 4; j++) {
        int ft = 4 * w + j;
#pragma unroll
        for (int kc = 0; kc < 4; kc++) {
            short8 a = *(const short8*)(W1 + (size_t)(ft * 16 + col) * 128 + kc * 32 + quad * 8);
            H[j] = __builtin_amdgcn_mfma_f32_16x16x32_bf16(a, xb[kc], H[j], 0, 0, 0);
        }
    }
#pragma unroll
    for (int cc = 0; cc < 2; cc++) {
        union { ushort u[8]; uint4 v; } pb;
#pragma unroll
        for (int i = 0; i < 8; i++)
            pb.u[i] = f2b(fmaxf(H[2 * cc + (i >> 2)][i & 3], 0.f));
        *(uint4*)(Hs + col * 264 + (2 * w + cc) * 32 + quad * 8) = pb.v;
    }
    __syncthreads();

    // ffn phase 2: et = 2w, 2w+1 over K=256; residual from Y[] registers
    f32x4 Y2[2] = {};
#pragma unroll
    for (int kc = 0; kc < 8; kc++) {
        short8 hb = *(const short8*)(Hs + col * 264 + kc * 32 + quad * 8);
#pragma unroll
        for (int j = 0; j < 2; j++) {
            int et = 2 * w + j;
            short8 a = *(const short8*)(W2P + (size_t)(et * 16 + col) * 256 + kc * 32 + quad * 8);
            Y2[j] = __builtin_amdgcn_mfma_f32_16x16x32_bf16(a, hb, Y2[j], 0, 0, 0);
        }
    }
    {
        union { ushort u[8]; uint4 v; } pb;
#pragma unroll
        for (int i = 0; i < 8; i++)
            pb.u[i] = f2b(Y2[i >> 2][i & 3] + Y[i >> 2][i & 3]);
        *(uint4*)(Ys + col * 136 + w * 32 + quad * 8) = pb.v;
    }
    __syncthreads();

    // ffn phase 3: conv, ot = w
    f32x4 O = {};
#pragma unroll
    for (int c = 0; c < 4; c++) {
        short8 yb = *(const short8*)(Ys + col * 136 + c * 32 + quad * 8);
        short8 a = *(const short8*)(WCP + (size_t)(w * 16 + col) * 128 + c * 32 + quad * 8);
        O = __builtin_amdgcn_mfma_f32_16x16x32_bf16(a, yb, O, 0, 0, 0);
    }
    const int l = l0 + col;
#pragma unroll
    for (int r2 = 0; r2 < 4; r2++) {
        int o = w * 16 + quad * 4 + r2;
        out[(size_t)(o * 25 + n) * 1024 + l] = O[r2];
    }
}

// ---------------------------------------------------------------------------
// Launch
// ---------------------------------------------------------------------------
extern "C" void kernel_launch(void* const* d_in, const int* in_sizes, int n_in,
                              void* d_out, int out_size, void* d_ws, size_t ws_size,
                              hipStream_t stream)
{
    const float* buffer   = (const float*)d_in[0];
    const float* spa      = (const float*)d_in[1];
    const float* w_mlp    = (const float*)d_in[2];
    const float* ln1_g    = (const float*)d_in[3];
    const float* ln1_b    = (const float*)d_in[4];
    const float* in_proj  = (const float*)d_in[5];
    const float* out_proj = (const float*)d_in[6];
    const float* ln2_g    = (const float*)d_in[7];
    const float* ln2_b    = (const float*)d_in[8];
    const float* ff_w1    = (const float*)d_in[9];
    const float* ff_w2    = (const float*)d_in[10];
    const float* conv_w   = (const float*)d_in[11];
    float* out = (float*)d_out;

    char* ws = (char*)d_ws;
    ushort* TOKb = (ushort*)(ws);                //  6,553,600 residual bf16
    ushort* Qh   = (ushort*)(ws + 6553600);      //  6,553,600 [n][h][l][d]
    ushort* Kh   = (ushort*)(ws + 13107200);     //  6,553,600
    ushort* VTg  = (ushort*)(ws + 19660800);     //  6,553,600 [n][h][y][d][xp]
    ushort* Wb   = (ushort*)(ws + 26214400);     //    425,984

    k_prep<<<dim3((W_TOTAL + 255) / 256), 256, 0, stream>>>(
        w_mlp, in_proj, out_proj, ff_w1, ff_w2, conv_w, Wb);
    k_tok_qkv<<<dim3(800), 256, 0, stream>>>(buffer, spa, Wb + OFF_W2,
                                             Wb + OFF_WQK, Wb + OFF_WV,
                                             ln1_g, ln1_b, TOKb, Qh, Kh, VTg);
    k_attn_ffn<<<dim3(1600), 256, 0, stream>>>(Qh, Kh, VTg, Wb + OFF_WO,
                                               ln2_g, ln2_b, Wb + OFF_W1,
                                               Wb + OFF_W2F, Wb + OFF_WC,
                                               TOKb, out);
}

// Round 11
// 172.425 us; speedup vs baseline: 1.0656x; 1.0118x over previous
//
#include <hip/hip_runtime.h>
#include <math.h>

// SpaTrans on MI355X. R11: R10 + ILP unlock.
//  * __launch_bounds__(256,4)/(256,3): R10's VGPR_Count=64 showed the
//    compiler capping regs for occupancy that LDS already forbids ->
//    serial chains. Raise the cap, keep loads in flight.
//  * k_attn_ffn: both heads interleaved (2 indep chains at every latency
//    point); softmax without max-subtract (|S|~0.05, shift-invariant);
//    Ys aliased onto Rs (LDS 22016->17664).
#define Lh 32
#define Lw 32
#define LL 1024
#define BN 25
#define EE 128
#define CC 64
#define NHD 8
#define DH 16
#define FFD 256
#define MROWS 25600

typedef __attribute__((ext_vector_type(8))) short short8;
typedef __attribute__((ext_vector_type(4))) float f32x4;

__device__ inline ushort f2b(float x) {
    union { float f; unsigned u; } v; v.f = x;
    unsigned r = (v.u + 0x7fffu + ((v.u >> 16) & 1u)) >> 16;
    return (ushort)r;
}
__device__ inline float b2f(ushort u) {
    union { unsigned u; float f; } v; v.u = ((unsigned)u) << 16;
    return v.f;
}

// ---------------------------------------------------------------------------
// Weight layout (ushorts). W2 K-reordered (k'=tap*64+ch). WO/W2F/WC k-PERMUTED
// (kpos=c*32+q*8+i <-> orig k=(2c+(i>>2))*16+q*4+(i&3)). Q rows pre-scaled 0.25.
// ---------------------------------------------------------------------------
#define OFF_W2  0
#define OFF_WQK 73728
#define OFF_WV  106496
#define OFF_WO  122880
#define OFF_W1  139264
#define OFF_W2F 172032
#define OFF_WC  204800
#define W_TOTAL 212992

__global__ __launch_bounds__(256) void k_prep(
    const float* __restrict__ w_mlp, const float* __restrict__ in_proj,
    const float* __restrict__ out_proj, const float* __restrict__ ff_w1,
    const float* __restrict__ ff_w2, const float* __restrict__ conv_w,
    ushort* __restrict__ Wb)
{
    int i = blockIdx.x * 256 + threadIdx.x;
    if (i >= W_TOTAL) return;
    if (i < 73728) {
        int e = i / 576, k = i - e * 576;
        int tap = k >> 6, ch = k & 63;
        Wb[OFF_W2 + i] = f2b(w_mlp[e * 576 + ch * 9 + tap]);
        return;
    }
    i -= 73728;
    if (i < 32768) {   // WQK; Q rows pre-scaled by 1/sqrt(16)
        float v = in_proj[i];
        Wb[OFF_WQK + i] = f2b(i < 16384 ? v * 0.25f : v);
        return;
    }
    i -= 32768;
    if (i < 16384) { Wb[OFF_WV + i] = f2b(in_proj[32768 + i]); return; }
    i -= 16384;
    if (i < 16384) {   // WO, k-permuted (K=128)
        int e = i >> 7, kpos = i & 127;
        int c = kpos >> 5, q = (kpos >> 3) & 3, ii = kpos & 7;
        int orig = (2 * c + (ii >> 2)) * 16 + q * 4 + (ii & 3);
        Wb[OFF_WO + i] = f2b(out_proj[e * 128 + orig]);
        return;
    }
    i -= 16384;
    if (i < 32768) { Wb[OFF_W1 + i] = f2b(ff_w1[i]); return; }
    i -= 32768;
    if (i < 32768) {   // W2F, k-permuted (K=256)
        int e = i >> 8, kpos = i & 255;
        int c = kpos >> 5, q = (kpos >> 3) & 3, ii = kpos & 7;
        int orig = (2 * c + (ii >> 2)) * 16 + q * 4 + (ii & 3);
        Wb[OFF_W2F + i] = f2b(ff_w2[e * 256 + orig]);
        return;
    }
    i -= 32768;
    {                  // WC, k-permuted (K=128)
        int o = i >> 7, kpos = i & 127;
        int c = kpos >> 5, q = (kpos >> 3) & 3, ii = kpos & 7;
        int orig = (2 * c + (ii >> 2)) * 16 + q * 4 + (ii & 3);
        Wb[OFF_WC + i] = f2b(conv_w[o * 128 + orig]);
    }
}

// ---------------------------------------------------------------------------
// Token embed + LN1 + QKV, input transpose fused (R10). Grid 800.
// LDS caps at 3 blocks/CU -> launch_bounds(256,3) frees VGPRs for ILP.
// ---------------------------------------------------------------------------
__global__ __launch_bounds__(256, 3) void k_tok_qkv(
    const float* __restrict__ buf, const float* __restrict__ spa,
    const ushort* __restrict__ W2, const ushort* __restrict__ WQK,
    const ushort* __restrict__ WV, const float* __restrict__ g1,
    const float* __restrict__ b1, ushort* __restrict__ TOKb,
    ushort* __restrict__ Qh, ushort* __restrict__ Kh, ushort* __restrict__ VTg)
{
    const int bid = blockIdx.x;                       // 800 blocks
    const int idx = (bid & 7) * 100 + (bid >> 3);     // XCD-contiguous chunks
    const int n = idx / 32, y = idx & 31;
    __shared__ ushort At[3 * 34 * 72];
    __shared__ ushort As_[3 * 34 * 72];
    __shared__ ushort Xs[32 * 136];   // phase A: aliased as t0 (fp32 [64][33])
    __shared__ ushort Vs[32 * 136];   // phase A: aliased as t1
    __shared__ float2 red[32][4];
    float* t0 = (float*)Xs;
    float* t1 = (float*)Vs;
    const int t = threadIdx.x;
    const uint4 z = make_uint4(0, 0, 0, 0);

    // ---- fused input transpose: 3 rows (y-1, y, y+1) ----
    for (int dy = 0; dy < 3; dy++) {
        int yy = y + dy - 1;
        if (yy >= 0 && yy < Lh) {
            {
                int ch = t >> 2, x8 = (t & 3) * 8;
                const float* p = buf + ((size_t)(ch * BN + n) * LL + yy * Lw + x8);
                const float* q = spa + ((size_t)(ch * BN + n) * LL + yy * Lw + x8);
                float4 a0 = ((const float4*)p)[0], a1 = ((const float4*)p)[1];
                float4 b0 = ((const float4*)q)[0], b1 = ((const float4*)q)[1];
                float* d0 = t0 + ch * 33 + x8;
                float* d1 = t1 + ch * 33 + x8;
                d0[0] = a0.x; d0[1] = a0.y; d0[2] = a0.z; d0[3] = a0.w;
                d0[4] = a1.x; d0[5] = a1.y; d0[6] = a1.z; d0[7] = a1.w;
                d1[0] = a0.x + b0.x; d1[1] = a0.y + b0.y; d1[2] = a0.z + b0.z; d1[3] = a0.w + b0.w;
                d1[4] = a1.x + b1.x; d1[5] = a1.y + b1.y; d1[6] = a1.z + b1.z; d1[7] = a1.w + b1.w;
            }
            __syncthreads();
            {
                int x = t >> 3, c8 = (t & 7) * 8;
                union { ushort u[8]; uint4 v; } o0, o1;
#pragma unroll
                for (int j = 0; j < 8; j++) {
                    o0.u[j] = f2b(t0[(c8 + j) * 33 + x]);
                    o1.u[j] = f2b(t1[(c8 + j) * 33 + x]);
                }
                *(uint4*)(At + (dy * 34 + x + 1) * 72 + c8) = o0.v;
                *(uint4*)(As_ + (dy * 34 + x + 1) * 72 + c8) = o1.v;
            }
            __syncthreads();
        } else {
            int x = t >> 3, c8 = (t & 7) * 8;
            *(uint4*)(At + (dy * 34 + x + 1) * 72 + c8) = z;
            *(uint4*)(As_ + (dy * 34 + x + 1) * 72 + c8) = z;
        }
    }
    if (t < 48) {   // zero pad columns (x=-1 and x=32)
        int dy = t / 16, rem = t % 16;
        int colp = (rem >> 3) * 33, c8p = (rem & 7) * 8;
        *(uint4*)(At + (dy * 34 + colp) * 72 + c8p) = z;
        *(uint4*)(As_ + (dy * 34 + colp) * 72 + c8p) = z;
    }
    __syncthreads();

    const int w = t >> 6, lane = t & 63;
    const int col = lane & 15, quad = lane >> 4;
    f32x4 accT[2][2] = {}, accS[2][2] = {};

    for (int tap = 0; tap < 9; tap++) {
        int dy = tap / 3, dx = tap % 3;
#pragma unroll
        for (int cc = 0; cc < 2; cc++) {
            int kg = tap * 64 + cc * 32 + quad * 8;
            short8 b0 = *(const short8*)(W2 + (size_t)(w * 32 + col) * 576 + kg);
            short8 bq = *(const short8*)(W2 + (size_t)(w * 32 + 16 + col) * 576 + kg);
            int abase = (dy * 34 + col + dx) * 72 + cc * 32 + quad * 8;
            short8 aT0 = *(const short8*)(At + abase);
            short8 aT1 = *(const short8*)(At + abase + 16 * 72);
            short8 aS0 = *(const short8*)(As_ + abase);
            short8 aS1 = *(const short8*)(As_ + abase + 16 * 72);
            accT[0][0] = __builtin_amdgcn_mfma_f32_16x16x32_bf16(aT0, b0, accT[0][0], 0, 0, 0);
            accT[0][1] = __builtin_amdgcn_mfma_f32_16x16x32_bf16(aT0, bq, accT[0][1], 0, 0, 0);
            accT[1][0] = __builtin_amdgcn_mfma_f32_16x16x32_bf16(aT1, b0, accT[1][0], 0, 0, 0);
            accT[1][1] = __builtin_amdgcn_mfma_f32_16x16x32_bf16(aT1, bq, accT[1][1], 0, 0, 0);
            accS[0][0] = __builtin_amdgcn_mfma_f32_16x16x32_bf16(aS0, b0, accS[0][0], 0, 0, 0);
            accS[0][1] = __builtin_amdgcn_mfma_f32_16x16x32_bf16(aS0, bq, accS[0][1], 0, 0, 0);
            accS[1][0] = __builtin_amdgcn_mfma_f32_16x16x32_bf16(aS1, b0, accS[1][0], 0, 0, 0);
            accS[1][1] = __builtin_amdgcn_mfma_f32_16x16x32_bf16(aS1, bq, accS[1][1], 0, 0, 0);
        }
    }

    // LN1 partial sums
#pragma unroll
    for (int mi = 0; mi < 2; mi++)
#pragma unroll
        for (int r = 0; r < 4; r++) {
            float a0 = accS[mi][0][r], a1 = accS[mi][1][r];
            float ss = a0 + a1, qq = a0 * a0 + a1 * a1;
#pragma unroll
            for (int m = 1; m < 16; m <<= 1) {
                ss += __shfl_xor(ss, m, 64);
                qq += __shfl_xor(qq, m, 64);
            }
            if (col == 0) red[mi * 16 + quad * 4 + r][w] = make_float2(ss, qq);
        }
    __syncthreads();

    const float ga = g1[w * 32 + col],      ba = b1[w * 32 + col];
    const float gb = g1[w * 32 + 16 + col], bb = b1[w * 32 + 16 + col];
#pragma unroll
    for (int mi = 0; mi < 2; mi++)
#pragma unroll
        for (int r = 0; r < 4; r++) {
            int x = mi * 16 + quad * 4 + r;
            float2 p0 = red[x][0], p1 = red[x][1], p2 = red[x][2], p3 = red[x][3];
            float mean = (p0.x + p1.x + p2.x + p3.x) * (1.f / 128.f);
            float var  = (p0.y + p1.y + p2.y + p3.y) * (1.f / 128.f) - mean * mean;
            float rstd = rsqrtf(var + 1e-5f);
            int e0 = w * 32 + col, e1 = w * 32 + 16 + col;
            Xs[x * 136 + e0] = f2b((accS[mi][0][r] - mean) * rstd * ga + ba);
            Xs[x * 136 + e1] = f2b((accS[mi][1][r] - mean) * rstd * gb + bb);
            Vs[x * 136 + e0] = f2b(accT[mi][0][r]);
            Vs[x * 136 + e1] = f2b(accT[mi][1][r]);
        }
    __syncthreads();

    // phase B: QKV. Wave w -> heads 2w, 2w+1; token tiles j=0,1.
    short8 xb[2][4], xv[2][4];
#pragma unroll
    for (int j = 0; j < 2; j++)
#pragma unroll
        for (int kc = 0; kc < 4; kc++) {
            xb[j][kc] = *(const short8*)(Xs + (j * 16 + col) * 136 + kc * 32 + quad * 8);
            xv[j][kc] = *(const short8*)(Vs + (j * 16 + col) * 136 + kc * 32 + quad * 8);
        }
    f32x4 Q[2][2] = {}, K[2][2] = {}, V[2][2] = {};
#pragma unroll
    for (int hj = 0; hj < 2; hj++) {
        int h = 2 * w + hj;
#pragma unroll
        for (int kc = 0; kc < 4; kc++) {
            short8 aq = *(const short8*)(WQK + (size_t)(h * 16 + col) * 128 + kc * 32 + quad * 8);
            short8 ak = *(const short8*)(WQK + (size_t)(128 + h * 16 + col) * 128 + kc * 32 + quad * 8);
            short8 av = *(const short8*)(WV + (size_t)(h * 16 + col) * 128 + kc * 32 + quad * 8);
#pragma unroll
            for (int j = 0; j < 2; j++) {
                Q[hj][j] = __builtin_amdgcn_mfma_f32_16x16x32_bf16(aq, xb[j][kc], Q[hj][j], 0, 0, 0);
                K[hj][j] = __builtin_amdgcn_mfma_f32_16x16x32_bf16(ak, xb[j][kc], K[hj][j], 0, 0, 0);
                V[hj][j] = __builtin_amdgcn_mfma_f32_16x16x32_bf16(av, xv[j][kc], V[hj][j], 0, 0, 0);
            }
        }
    }
    ushort* VTs = At;   // dead after MFMA loop; [8 heads][16 d][stride 34]
#pragma unroll
    for (int hj = 0; hj < 2; hj++) {
        int h = 2 * w + hj;
#pragma unroll
        for (int j = 0; j < 2; j++) {
            int l = y * 32 + j * 16 + col;
            size_t base = ((size_t)(n * 8 + h) * 1024 + l) * 16 + quad * 4;
            ushort4 oq, ok;
            oq.x = f2b(Q[hj][j][0]); oq.y = f2b(Q[hj][j][1]); oq.z = f2b(Q[hj][j][2]); oq.w = f2b(Q[hj][j][3]);
            ok.x = f2b(K[hj][j][0]); ok.y = f2b(K[hj][j][1]); ok.z = f2b(K[hj][j][2]); ok.w = f2b(K[hj][j][3]);
            *(ushort4*)(Qh + base) = oq;
            *(ushort4*)(Kh + base) = ok;
            int xp = ((col >> 2) << 3) + (j << 2) + (col & 3);
#pragma unroll
            for (int r = 0; r < 4; r++)
                VTs[(h * 16 + quad * 4 + r) * 34 + xp] = f2b(V[hj][j][r]);
        }
    }
#pragma unroll
    for (int k = 0; k < 2; k++) {
        int idx2 = t + k * 256;
        int r = idx2 >> 4, seg = idx2 & 15;
        *(uint4*)(TOKb + ((size_t)((y * 32 + r) * 25 + n)) * 128 + seg * 8) =
            *(const uint4*)(Vs + r * 136 + seg * 8);
    }
    __syncthreads();
    {   // coalesced VTg write
        int h = t >> 5, rem = t & 31, d = rem >> 1, xh = (rem & 1) * 16;
        size_t vrow = ((size_t)(n * 8 + h) * 32 + y) * 512;
        union { ushort u[8]; uint4 v; } o0, o1;
#pragma unroll
        for (int j = 0; j < 8; j++) {
            o0.u[j] = VTs[(h * 16 + d) * 34 + xh + j];
            o1.u[j] = VTs[(h * 16 + d) * 34 + xh + 8 + j];
        }
        *(uint4*)(VTg + vrow + d * 32 + xh)     = o0.v;
        *(uint4*)(VTg + vrow + d * 32 + xh + 8) = o1.v;
    }
}

// ---------------------------------------------------------------------------
// Attention + out_proj + residual + LN2 + FFN + conv, fully fused.
// Grid 1600 (n,y,half). Both heads INTERLEAVED; softmax without max;
// Ys aliased on Rs. launch_bounds(256,4) -> VGPR cap 128 for ILP.
// ---------------------------------------------------------------------------
__global__ __launch_bounds__(256, 4) void k_attn_ffn(
    const ushort* __restrict__ Qh, const ushort* __restrict__ Kh,
    const ushort* __restrict__ VTg, const ushort* __restrict__ WOP,
    const float* __restrict__ g2, const float* __restrict__ b2,
    const ushort* __restrict__ W1, const ushort* __restrict__ W2P,
    const ushort* __restrict__ WCP, const ushort* __restrict__ TOKb,
    float* __restrict__ out)
{
    __shared__ ushort OX[16 * 136];
    __shared__ ushort Rs[16 * 136];   // residual; later aliased as Ys
    __shared__ ushort Hs[16 * 264];
    __shared__ float2 red[16][4];
    ushort* Ys = Rs;                  // Rs dead 3 barriers before Ys write
    const int bid = blockIdx.x;                       // 1600 blocks
    const int idx = (bid & 7) * 200 + (bid >> 3);     // XCD-contiguous chunks
    const int n = idx / 64, rem = idx & 63;
    const int y = rem >> 1, half = rem & 1;
    const int l0 = y * 32 + half * 16;
    const int t = threadIdx.x, w = t >> 6, lane = t & 63;
    const int col = lane & 15, quad = lane >> 4;
    const int qx = half * 16 + col;

    {   // stage residual rows (16 tokens, bf16)
        int r = t >> 4, seg = t & 15;
        *(uint4*)(Rs + r * 136 + seg * 8) =
            *(const uint4*)(TOKb + ((size_t)((l0 + r) * 25 + n)) * 128 + seg * 8);
    }

    // hoisted mask bits (head-independent)
    unsigned long long mbits = 0;
#pragma unroll
    for (int tt = 0; tt < 10; tt++) {
        int yy = y - 2 + (tt >> 1);
        bool rok = (yy >= 0) && (yy < 32);
        int kxb = ((tt & 1) << 4) + quad * 4;
#pragma unroll
        for (int r = 0; r < 4; r++) {
            int dd = kxb + r - qx;
            if (rok && ((unsigned)(dd + 2) <= 4u))
                mbits |= 1ull << (tt * 4 + r);
        }
    }

    short8 z8 = {0, 0, 0, 0, 0, 0, 0, 0};
    const size_t base0 = (size_t)(n * 8 + 2 * w) * 1024;
    const size_t base1 = base0 + 1024;
    const size_t vbase0 = (size_t)(n * 8 + 2 * w) * 32 * 512;
    const size_t vbase1 = vbase0 + 32 * 512;

    // both heads' Q frags
    short8 qf0 = z8, qf1 = z8;
    if (quad < 2) {
        qf0 = *(const short8*)(Qh + (base0 + y * 32 + half * 16 + col) * 16 + quad * 8);
        qf1 = *(const short8*)(Qh + (base1 + y * 32 + half * 16 + col) * 16 + quad * 8);
    }

    // scores, interleaved
    f32x4 Sc[2][10] = {};
#pragma unroll
    for (int tt = 0; tt < 10; tt++) {
        int kr = tt >> 1, kx = ((tt & 1) << 4) + col;
        int yyc = min(max(y - 2 + kr, 0), 31);
        short8 kf0 = z8, kf1 = z8;
        if (quad < 2) {
            kf0 = *(const short8*)(Kh + (base0 + yyc * 32 + kx) * 16 + quad * 8);
            kf1 = *(const short8*)(Kh + (base1 + yyc * 32 + kx) * 16 + quad * 8);
        }
        Sc[0][tt] = __builtin_amdgcn_mfma_f32_16x16x32_bf16(kf0, qf0, Sc[0][tt], 0, 0, 0);
        Sc[1][tt] = __builtin_amdgcn_mfma_f32_16x16x32_bf16(kf1, qf1, Sc[1][tt], 0, 0, 0);
    }

    // softmax WITHOUT max-subtraction (|S| ~ 0.05; shift-invariant)
    float sum0 = 0.f, sum1 = 0.f;
#pragma unroll
    for (int tt = 0; tt < 10; tt++)
#pragma unroll
        for (int r = 0; r < 4; r++) {
            bool ok = (mbits >> (tt * 4 + r)) & 1;
            float p0 = ok ? __expf(Sc[0][tt][r]) : 0.f;
            float p1 = ok ? __expf(Sc[1][tt][r]) : 0.f;
            Sc[0][tt][r] = p0; Sc[1][tt][r] = p1;
            sum0 += p0; sum1 += p1;
        }
    sum0 += __shfl_xor(sum0, 16, 64); sum0 += __shfl_xor(sum0, 32, 64);
    sum1 += __shfl_xor(sum1, 16, 64); sum1 += __shfl_xor(sum1, 32, 64);
    const float inv0 = 1.f / sum0, inv1 = 1.f / sum1;

    // PV interleaved: A-frags from VTg; P packed UNNORMALIZED
    f32x4 O20 = {}, O21 = {};
#pragma unroll
    for (int c = 0; c < 5; c++) {
        int yyc = min(max(y - 2 + c, 0), 31);
        short8 vt0 = *(const short8*)(VTg + vbase0 + (size_t)yyc * 512 + col * 32 + quad * 8);
        short8 vt1 = *(const short8*)(VTg + vbase1 + (size_t)yyc * 512 + col * 32 + quad * 8);
        union { ushort u[8]; short8 s; } pb0, pb1;
#pragma unroll
        for (int i = 0; i < 8; i++) {
            pb0.u[i] = f2b(Sc[0][2 * c + (i >> 2)][i & 3]);
            pb1.u[i] = f2b(Sc[1][2 * c + (i >> 2)][i & 3]);
        }
        O20 = __builtin_amdgcn_mfma_f32_16x16x32_bf16(vt0, pb0.s, O20, 0, 0, 0);
        O21 = __builtin_amdgcn_mfma_f32_16x16x32_bf16(vt1, pb1.s, O21, 0, 0, 0);
    }
#pragma unroll
    for (int r = 0; r < 4; r++) { O20[r] *= inv0; O21[r] *= inv1; }

    // pack O (heads 2w,2w+1) -> OX as B-operand k-slice w
    {
        union { ushort u[8]; uint4 v; } pb;
#pragma unroll
        for (int i = 0; i < 4; i++) { pb.u[i] = f2b(O20[i]); pb.u[4 + i] = f2b(O21[i]); }
        *(uint4*)(OX + col * 136 + w * 32 + quad * 8) = pb.v;
    }
    __syncthreads();

    // out_proj: wave w -> e-tiles {2w, 2w+1}
    f32x4 Y[2] = {};
#pragma unroll
    for (int kc = 0; kc < 4; kc++) {
        short8 hb = *(const short8*)(OX + col * 136 + kc * 32 + quad * 8);
#pragma unroll
        for (int jj = 0; jj < 2; jj++) {
            int et = 2 * w + jj;
            short8 a = *(const short8*)(WOP + (size_t)(et * 16 + col) * 128 + kc * 32 + quad * 8);
            Y[jj] = __builtin_amdgcn_mfma_f32_16x16x32_bf16(a, hb, Y[jj], 0, 0, 0);
        }
    }
    // residual + LN2 stats (token = col); tok2 stays in Y[] registers
    float sum = 0.f, sq = 0.f;
#pragma unroll
    for (int jj = 0; jj < 2; jj++)
#pragma unroll
        for (int r = 0; r < 4; r++) {
            int e = (2 * w + jj) * 16 + quad * 4 + r;
            float v = Y[jj][r] + b2f(Rs[col * 136 + e]);
            Y[jj][r] = v;
            sum += v; sq += v * v;
        }
    sum += __shfl_xor(sum, 16, 64); sum += __shfl_xor(sum, 32, 64);
    sq  += __shfl_xor(sq, 16, 64);  sq  += __shfl_xor(sq, 32, 64);
    if (quad == 0) red[col][w] = make_float2(sum, sq);
    __syncthreads();

    {
        float2 p0 = red[col][0], p1 = red[col][1], p2 = red[col][2], p3 = red[col][3];
        float mean = (p0.x + p1.x + p2.x + p3.x) * (1.f / 128.f);
        float var  = (p0.y + p1.y + p2.y + p3.y) * (1.f / 128.f) - mean * mean;
        float rstd = rsqrtf(var + 1e-5f);
#pragma unroll
        for (int jj = 0; jj < 2; jj++)
#pragma unroll
            for (int r = 0; r < 4; r++) {
                int e = (2 * w + jj) * 16 + quad * 4 + r;
                OX[col * 136 + e] = f2b((Y[jj][r] - mean) * rstd * g2[e] + b2[e]);
            }
    }
    __syncthreads();

    // ffn phase 1: ft = 4w..4w+3 over K=128 from OX
    short8 xb[4];
#pragma unroll
    for (int kc = 0; kc < 4; kc++)
        xb[kc] = *(const short8*)(OX + col * 136 + kc * 32 + quad * 8);
    f32x4 H[4] = {};
#pragma unroll
    for (int j = 0; j < 4; j++) {
        int ft = 4 * w + j;
#pragma unroll
        for (int kc = 0; kc < 4; kc++) {
            short8 a = *(const short8*)(W1 + (size_t)(ft * 16 + col) * 128 + kc * 32 + quad * 8);
            H[j] = __builtin_amdgcn_mfma_f32_16x16x32_bf16(a, xb[kc], H[j], 0, 0, 0);
        }
    }
#pragma unroll
    for (int cc = 0; cc < 2; cc++) {
        union { ushort u[8]; uint4 v; } pb;
#pragma unroll
        for (int i = 0; i < 8; i++)
            pb.u[i] = f2b(fmaxf(H[2 * cc + (i >> 2)][i & 3], 0.f));
        *(uint4*)(Hs + col * 264 + (2 * w + cc) * 32 + quad * 8) = pb.v;
    }
    __syncthreads();

    // ffn phase 2: et = 2w, 2w+1 over K=256; residual from Y[] registers
    f32x4 Y2[2] = {};
#pragma unroll
    for (int kc = 0; kc < 8; kc++) {
        short8 hb = *(const short8*)(Hs + col * 264 + kc * 32 + quad * 8);
#pragma unroll
        for (int j = 0; j < 2; j++) {
            int et = 2 * w + j;
            short8 a = *(const short8*)(W2P + (size_t)(et * 16 + col) * 256 + kc * 32 + quad * 8);
            Y2[j] = __builtin_amdgcn_mfma_f32_16x16x32_bf16(a, hb, Y2[j], 0, 0, 0);
        }
    }
    {
        union { ushort u[8]; uint4 v; } pb;
#pragma unroll
        for (int i = 0; i < 8; i++)
            pb.u[i] = f2b(Y2[i >> 2][i & 3] + Y[i >> 2][i & 3]);
        *(uint4*)(Ys + col * 136 + w * 32 + quad * 8) = pb.v;
    }
    __syncthreads();

    // ffn phase 3: conv, ot = w
    f32x4 O = {};
#pragma unroll
    for (int c = 0; c < 4; c++) {
        short8 yb = *(const short8*)(Ys + col * 136 + c * 32 + quad * 8);
        short8 a = *(const short8*)(WCP + (size_t)(w * 16 + col) * 128 + c * 32 + quad * 8);
        O = __builtin_amdgcn_mfma_f32_16x16x32_bf16(a, yb, O, 0, 0, 0);
    }
    const int l = l0 + col;
#pragma unroll
    for (int r2 = 0; r2 < 4; r2++) {
        int o = w * 16 + quad * 4 + r2;
        out[(size_t)(o * 25 + n) * 1024 + l] = O[r2];
    }
}

// ---------------------------------------------------------------------------
// Launch
// ---------------------------------------------------------------------------
extern "C" void kernel_launch(void* const* d_in, const int* in_sizes, int n_in,
                              void* d_out, int out_size, void* d_ws, size_t ws_size,
                              hipStream_t stream)
{
    const float* buffer   = (const float*)d_in[0];
    const float* spa      = (const float*)d_in[1];
    const float* w_mlp    = (const float*)d_in[2];
    const float* ln1_g    = (const float*)d_in[3];
    const float* ln1_b    = (const float*)d_in[4];
    const float* in_proj  = (const float*)d_in[5];
    const float* out_proj = (const float*)d_in[6];
    const float* ln2_g    = (const float*)d_in[7];
    const float* ln2_b    = (const float*)d_in[8];
    const float* ff_w1    = (const float*)d_in[9];
    const float* ff_w2    = (const float*)d_in[10];
    const float* conv_w   = (const float*)d_in[11];
    float* out = (float*)d_out;

    char* ws = (char*)d_ws;
    ushort* TOKb = (ushort*)(ws);                //  6,553,600 residual bf16
    ushort* Qh   = (ushort*)(ws + 6553600);      //  6,553,600 [n][h][l][d]
    ushort* Kh   = (ushort*)(ws + 13107200);     //  6,553,600
    ushort* VTg  = (ushort*)(ws + 19660800);     //  6,553,600 [n][h][y][d][xp]
    ushort* Wb   = (ushort*)(ws + 26214400);     //    425,984

    k_prep<<<dim3((W_TOTAL + 255) / 256), 256, 0, stream>>>(
        w_mlp, in_proj, out_proj, ff_w1, ff_w2, conv_w, Wb);
    k_tok_qkv<<<dim3(800), 256, 0, stream>>>(buffer, spa, Wb + OFF_W2,
                                             Wb + OFF_WQK, Wb + OFF_WV,
                                             ln1_g, ln1_b, TOKb, Qh, Kh, VTg);
    k_attn_ffn<<<dim3(1600), 256, 0, stream>>>(Qh, Kh, VTg, Wb + OFF_WO,
                                               ln2_g, ln2_b, Wb + OFF_W1,
                                               Wb + OFF_W2F, Wb + OFF_WC,
                                               TOKb, out);
}